// Round 2
// baseline (89.732 us; speedup 1.0000x reference)
//
#include <hip/hip_runtime.h>
#include <hip/hip_bf16.h>
#include <cstdint>

#define NV 64
#define NH 128
#define NB 16384
#define NCHUNK 37                 // 8 diag + 28 off-diag + 1 order-1, 64 k each
#define FRAG_ELEMS (NCHUNK * 8192)  // 303104 bf16 = 592 KB in d_ws

typedef __bf16 bf16x8_t __attribute__((ext_vector_type(8)));
typedef float f32x4_t __attribute__((ext_vector_type(4)));
typedef float f32x2_t __attribute__((ext_vector_type(2)));
typedef uint32_t u32x4_t __attribute__((ext_vector_type(4)));
typedef uint32_t u32x2_t __attribute__((ext_vector_type(2)));

__device__ __forceinline__ uint32_t bf16_rne(float f) {
  uint32_t u = __float_as_uint(f);
  return (u + 0x7fffu + ((u >> 16) & 1u)) >> 16;
}

// Pre-pass: build B' in MFMA-B-fragment order, symmetrized group-triangle:
//  chunk c<8 (diag, I=J=c):    B'[h, slot(a,b)] = 0.5*W2[h, I8+a, I8+b]
//  chunk 8..35 (off, I<J):     B'[h, slot(a,b)] = 0.5*(W2[h,i,j]+W2[h,j,i])
//  chunk 36 (order-1):         B'[h, slot=j]    = W1[j, h]
// Fragment (c2 = c*2+jh, fh): lane l holds B'[h = fh*16+(l&15)]
//   [k = slot = jh*32 + (l>>4)*8 + t], elem offset ((c2*8+fh)*512 + l*8 + t).
__global__ void cvt_kernel(const float* __restrict__ w1f,
                           const float* __restrict__ w2f,
                           uint16_t* __restrict__ frag) {
  int tg = blockIdx.x * 256 + threadIdx.x;   // < 74*8*64 = 37888
  int l = tg & 63, fh = (tg >> 6) & 7, c2 = tg >> 9;
  int chunk = c2 >> 1, jh = c2 & 1;
  int h = fh * 16 + (l & 15);
  int kb = jh * 32 + (l >> 4) * 8;
  uint32_t o16[8];
#pragma unroll
  for (int t = 0; t < 8; ++t) {
    int slot = kb + t;
    float v;
    if (chunk < 8) {
      int i = chunk * 8 + (slot >> 3), j = chunk * 8 + (slot & 7);
      v = 0.5f * w2f[h * 4096 + i * 64 + j];
    } else if (chunk < 36) {
      int o = chunk - 8, I = 0;
      while (o >= 7 - I) { o -= 7 - I; ++I; }
      int J = I + 1 + o;
      int i = I * 8 + (slot >> 3), j = J * 8 + (slot & 7);
      v = 0.5f * (w2f[h * 4096 + i * 64 + j] + w2f[h * 4096 + j * 64 + i]);
    } else {
      v = w1f[slot * 128 + h];
    }
    o16[t] = bf16_rne(v);
  }
  uint4 o;
  o.x = (o16[1] << 16) | o16[0];
  o.y = (o16[3] << 16) | o16[2];
  o.z = (o16[5] << 16) | o16[4];
  o.w = (o16[7] << 16) | o16[6];
  *(uint4*)(frag + ((size_t)(c2 * 8 + fh) << 9) + l * 8) = o;
}

// psi[m] = prod_h cos(bias[h] + sum_k A[m,k] B'[h,k]), K = 37*64.
// v3: wave = 16 rows x 64 h-cols (ih=4). The afrag build (the VALU cost) is
// now shared across 4 MFMAs instead of 2: 2 VALU/MFMA (was 4), chip-wide
// K-loop VALU halves. 8 waves = 4 row-sixteens x 2 h-halves, 64 rows/block,
// grid 256 (1 block/CU). Depth-1 register prefetch of B-frags, zero barriers
// in the K-loop. VGPR ~135 -> 2 waves/SIMD (occupancy proven non-binding in
// rounds 0-1; the kernel is VALU-work-bound).
__launch_bounds__(512, 2)
__global__ void rbm_kernel(const float* __restrict__ xg,
                           const float* __restrict__ biasg,
                           const __hip_bfloat16* __restrict__ frag,
                           float* __restrict__ outg) {
  __shared__ __align__(16) float xtile[64 * 76];
  __shared__ float part[2][64];

  const int tid  = threadIdx.x;
  const int wv   = tid >> 6;
  const int wm   = wv & 3;     // row sixteen (0..3)
  const int hq   = wv >> 2;    // h half (64 cols)
  const int lane = tid & 63;
  const int c15  = lane & 15;
  const int q    = lane >> 4;
  const int mblk = blockIdx.x * 64;

  // chunk -> (I, J) tables (compile-time folded under full unroll)
  constexpr int CI[36] = {0,1,2,3,4,5,6,7, 0,0,0,0,0,0,0, 1,1,1,1,1,1,
                          2,2,2,2,2, 3,3,3,3, 4,4,4, 5,5, 6};
  constexpr int CJ[36] = {0,1,2,3,4,5,6,7, 1,2,3,4,5,6,7, 2,3,4,5,6,7,
                          3,4,5,6,7, 4,5,6,7, 5,6,7, 6,7, 7};

  // stage x tile (64 rows x 64 f32, stride 76)
  {
    int row = tid >> 3, grp = tid & 7;
    const float* p = xg + (size_t)(mblk + row) * NV + grp * 8;
    float4 a = *(const float4*)(p);
    float4 b4 = *(const float4*)(p + 4);
    *(float4*)(&xtile[row * 76 + grp * 8]) = a;
    *(float4*)(&xtile[row * 76 + grp * 8 + 4]) = b4;
  }
  __syncthreads();

  // this lane's single m-row: LDS base + full row cached in regs (f32 pairs)
  const float* sx = &xtile[(wm * 16 + c15) * 76];
  f32x2_t xb[32];   // xb[g*4+tt] = {x[g*8+2tt], x[g*8+2tt+1]}
#pragma unroll
  for (int g = 0; g < 8; ++g) {
    float4 a = *(const float4*)(sx + g * 8);
    float4 b4 = *(const float4*)(sx + g * 8 + 4);
    xb[g * 4 + 0] = f32x2_t{a.x, a.y};
    xb[g * 4 + 1] = f32x2_t{a.z, a.w};
    xb[g * 4 + 2] = f32x2_t{b4.x, b4.y};
    xb[g * 4 + 3] = f32x2_t{b4.z, b4.w};
  }

  // B-fragment base: wave covers fh = hq*4 + ih (ih 0..3), lane offset l*8
  const __hip_bfloat16* pw = frag + (size_t)hq * 2048 + lane * 8;

  f32x4_t acc[4];
#pragma unroll
  for (int ih = 0; ih < 4; ++ih)
    acc[ih] = (f32x4_t)0.0f;

  // depth-1 prefetch buffer: b[jh][ih] holds chunk-c frags during chunk c
  bf16x8_t b[2][4];
#pragma unroll
  for (int jh = 0; jh < 2; ++jh)
#pragma unroll
    for (int ih = 0; ih < 4; ++ih)
      b[jh][ih] = *(const bf16x8_t*)(pw + jh * 4096 + ih * 512);

#pragma unroll
  for (int c = 0; c < 36; ++c) {
    const int I = CI[c], J = CJ[c];
    const __hip_bfloat16* pn = pw + (size_t)(c + 1) * 8192;
#pragma unroll
    for (int jh = 0; jh < 2; ++jh) {
      // build the ONE afrag this wave needs for this (c, jh): 8 VALU ops
      float s = sx[I * 8 + jh * 4 + q];   // LDS b32, 2-way max conflict
      const f32x2_t s2 = f32x2_t{s, s};
      u32x4_t adv;
#pragma unroll
      for (int tt = 0; tt < 4; ++tt) {
        f32x2_t pr = s2 * xb[J * 4 + tt];          // v_pk_mul_f32
        u32x2_t u = __builtin_bit_cast(u32x2_t, pr);
        adv[tt] = __builtin_amdgcn_perm(u[1], u[0], 0x07060302);
      }
      bf16x8_t afrag = __builtin_bit_cast(bf16x8_t, adv);
      // 4 MFMAs share it; reload each b slot for chunk c+1 right after use
#pragma unroll
      for (int ih = 0; ih < 4; ++ih) {
        acc[ih] = __builtin_amdgcn_mfma_f32_16x16x32_bf16(
            afrag, b[jh][ih], acc[ih], 0, 0, 0);
        b[jh][ih] = *(const bf16x8_t*)(pn + jh * 4096 + ih * 512);
      }
    }
  }

  // order-1 tail (chunk 36, b[] holds its frags): A = x_j straight from LDS
#pragma unroll
  for (int jh = 0; jh < 2; ++jh) {
    float4 a = *(const float4*)(sx + jh * 32 + q * 8);
    float4 b4 = *(const float4*)(sx + jh * 32 + q * 8 + 4);
    const float pr[4][2] = {{a.x, a.y}, {a.z, a.w}, {b4.x, b4.y}, {b4.z, b4.w}};
    u32x4_t adv;
#pragma unroll
    for (int tt = 0; tt < 4; ++tt)
      adv[tt] = __builtin_amdgcn_perm(__float_as_uint(pr[tt][1]),
                                      __float_as_uint(pr[tt][0]), 0x07060302);
    bf16x8_t af = __builtin_bit_cast(bf16x8_t, adv);
#pragma unroll
    for (int ih = 0; ih < 4; ++ih)
      acc[ih] = __builtin_amdgcn_mfma_f32_16x16x32_bf16(
          af, b[jh][ih], acc[ih], 0, 0, 0);
  }

  // epilogue: a += bias; hw cos (input in revolutions); product over h
  float bs[4];
#pragma unroll
  for (int ih = 0; ih < 4; ++ih)
    bs[ih] = biasg[hq * 64 + ih * 16 + c15];

  const float INV2PI = 0.15915494309189535f;
  float prod[4];
#pragma unroll
  for (int r = 0; r < 4; ++r) {
    float c0 = __builtin_amdgcn_cosf((acc[0][r] + bs[0]) * INV2PI);
    float c1 = __builtin_amdgcn_cosf((acc[1][r] + bs[1]) * INV2PI);
    float c2 = __builtin_amdgcn_cosf((acc[2][r] + bs[2]) * INV2PI);
    float c3 = __builtin_amdgcn_cosf((acc[3][r] + bs[3]) * INV2PI);
    prod[r] = (c0 * c1) * (c2 * c3);
  }

  // product across the 16 h-columns held by lanes (width-16 butterfly)
#pragma unroll
  for (int ofs = 1; ofs < 16; ofs <<= 1)
#pragma unroll
    for (int r = 0; r < 4; ++r)
      prod[r] *= __shfl_xor(prod[r], ofs, 16);

  if (c15 == 0) {
#pragma unroll
    for (int r = 0; r < 4; ++r)
      part[hq][wm * 16 + q * 4 + r] = prod[r];
  }
  __syncthreads();
  if (tid < 64) {
    float f = part[0][tid] * part[1][tid];
    outg[mblk + tid] = f;
  }
}

extern "C" void kernel_launch(void* const* d_in, const int* in_sizes, int n_in,
                              void* d_out, int out_size, void* d_ws, size_t ws_size,
                              hipStream_t stream) {
  const float* x   = (const float*)d_in[0];
  const float* w1f = (const float*)d_in[1];
  const float* w2f = (const float*)d_in[2];
  const float* hb  = (const float*)d_in[3];
  float* out = (float*)d_out;
  uint16_t* frag = (uint16_t*)d_ws;   // FRAG_ELEMS bf16 (592 KB)
  (void)in_sizes; (void)n_in; (void)out_size; (void)ws_size;

  cvt_kernel<<<148, 256, 0, stream>>>(w1f, w2f, frag);
  rbm_kernel<<<NB / 64, 512, 0, stream>>>(
      x, hb, (const __hip_bfloat16*)frag, out);
}

// Round 3
// 86.209 us; speedup vs baseline: 1.0409x; 1.0409x over previous
//
#include <hip/hip_runtime.h>
#include <hip/hip_bf16.h>
#include <cstdint>

#define NV 64
#define NH 128
#define NB 16384
#define NCHUNK 37                 // 8 diag + 28 off-diag + 1 order-1, 64 k each
#define FRAG_ELEMS (NCHUNK * 8192)  // 303104 bf16 = 592 KB in d_ws

typedef __bf16 bf16x8_t __attribute__((ext_vector_type(8)));
typedef float f32x4_t __attribute__((ext_vector_type(4)));
typedef float f32x2_t __attribute__((ext_vector_type(2)));
typedef uint32_t u32x4_t __attribute__((ext_vector_type(4)));
typedef uint32_t u32x2_t __attribute__((ext_vector_type(2)));

__device__ __forceinline__ uint32_t bf16_rne(float f) {
  uint32_t u = __float_as_uint(f);
  return (u + 0x7fffu + ((u >> 16) & 1u)) >> 16;
}

// Pre-pass: build B' in MFMA-B-fragment order, symmetrized group-triangle:
//  chunk c<8 (diag, I=J=c):    B'[h, slot(a,b)] = 0.5*W2[h, I8+a, I8+b]
//  chunk 8..35 (off, I<J):     B'[h, slot(a,b)] = 0.5*(W2[h,i,j]+W2[h,j,i])
//  chunk 36 (order-1):         B'[h, slot=j]    = W1[j, h]
// Fragment (c2 = c*2+jh, fh): lane l holds B'[h = fh*16+(l&15)]
//   [k = slot = jh*32 + (l>>4)*8 + t], elem offset ((c2*8+fh)*512 + l*8 + t).
__global__ void cvt_kernel(const float* __restrict__ w1f,
                           const float* __restrict__ w2f,
                           uint16_t* __restrict__ frag) {
  int tg = blockIdx.x * 256 + threadIdx.x;   // < 74*8*64 = 37888
  int l = tg & 63, fh = (tg >> 6) & 7, c2 = tg >> 9;
  int chunk = c2 >> 1, jh = c2 & 1;
  int h = fh * 16 + (l & 15);
  int kb = jh * 32 + (l >> 4) * 8;
  uint32_t o16[8];
#pragma unroll
  for (int t = 0; t < 8; ++t) {
    int slot = kb + t;
    float v;
    if (chunk < 8) {
      int i = chunk * 8 + (slot >> 3), j = chunk * 8 + (slot & 7);
      v = 0.5f * w2f[h * 4096 + i * 64 + j];
    } else if (chunk < 36) {
      int o = chunk - 8, I = 0;
      while (o >= 7 - I) { o -= 7 - I; ++I; }
      int J = I + 1 + o;
      int i = I * 8 + (slot >> 3), j = J * 8 + (slot & 7);
      v = 0.5f * (w2f[h * 4096 + i * 64 + j] + w2f[h * 4096 + j * 64 + i]);
    } else {
      v = w1f[slot * 128 + h];
    }
    o16[t] = bf16_rne(v);
  }
  uint4 o;
  o.x = (o16[1] << 16) | o16[0];
  o.y = (o16[3] << 16) | o16[2];
  o.z = (o16[5] << 16) | o16[4];
  o.w = (o16[7] << 16) | o16[6];
  *(uint4*)(frag + ((size_t)(c2 * 8 + fh) << 9) + l * 8) = o;
}

// psi[m] = prod_h cos(bias[h] + sum_k A[m,k] B'[h,k]), K = 37*64.
// Main chunks: A[m, slot(a,b)] = x[m, I8+a] * x[m, J8+b]; s = x[I8+a] from LDS
// (a = jh*4+q static per jh), xB = group-J row registers. Tail: A = x_j.
// 8 waves = 2 m-halves x 4 h-quarters; grid 256 -> 2 waves/SIMD; K-loop fully
// unrolled, zero barriers, depth-1 register prefetch of B-frags (L1 dedups the
// m-half wave pair's identical B reads).
// NOTE (session journal): v1 (32 rows/block, 4 waves/SIMD) and v2 (ih=4,
// 2 VALU/MFMA) both measured neutral-to-worse (87.1 / 89.7 vs 86.55) — the
// kernel is a ~3.5 us latency-shaped slice under an ~81 us harness poison
// floor (2x 256 MiB fills at 82% HBM peak). This v0 structure is the best
// measured; keep it.
__launch_bounds__(512, 2)
__global__ void rbm_kernel(const float* __restrict__ xg,
                           const float* __restrict__ biasg,
                           const __hip_bfloat16* __restrict__ frag,
                           float* __restrict__ outg) {
  __shared__ __align__(16) float xtile[64 * 76];  // cols 64..71 = 1.0 sentinel
  __shared__ float part[4][64];

  const int tid  = threadIdx.x;
  const int wv   = tid >> 6;
  const int wm   = wv & 1;     // m half (32 rows)
  const int hq   = wv >> 1;    // h quarter (32 cols)
  const int lane = tid & 63;
  const int c15  = lane & 15;
  const int q    = lane >> 4;
  const int mblk = blockIdx.x * 64;

  // chunk -> (I, J) tables (compile-time folded under full unroll)
  constexpr int CI[36] = {0,1,2,3,4,5,6,7, 0,0,0,0,0,0,0, 1,1,1,1,1,1,
                          2,2,2,2,2, 3,3,3,3, 4,4,4, 5,5, 6};
  constexpr int CJ[36] = {0,1,2,3,4,5,6,7, 1,2,3,4,5,6,7, 2,3,4,5,6,7,
                          3,4,5,6,7, 4,5,6,7, 5,6,7, 6,7, 7};

  // stage x tile (64 rows x 64 f32, stride 76) + sentinel cols
  {
    int row = tid >> 3, grp = tid & 7;
    const float* p = xg + (size_t)(mblk + row) * NV + grp * 8;
    float4 a = *(const float4*)(p);
    float4 b = *(const float4*)(p + 4);
    *(float4*)(&xtile[row * 76 + grp * 8]) = a;
    *(float4*)(&xtile[row * 76 + grp * 8 + 4]) = b;
    xtile[row * 76 + 64 + grp] = 1.0f;
  }
  __syncthreads();

  // per-lane full x rows (f32 pairs) for the two m-rows this lane owns
  const float* sx[2];
  f32x2_t xb[2][32];   // xb[im][g*4+tt] = {x[g*8+2tt], x[g*8+2tt+1]}
#pragma unroll
  for (int im = 0; im < 2; ++im) {
    sx[im] = &xtile[(wm * 32 + im * 16 + c15) * 76];
#pragma unroll
    for (int g = 0; g < 8; ++g) {
      float4 a = *(const float4*)(sx[im] + g * 8);
      float4 b = *(const float4*)(sx[im] + g * 8 + 4);
      xb[im][g * 4 + 0] = f32x2_t{a.x, a.y};
      xb[im][g * 4 + 1] = f32x2_t{a.z, a.w};
      xb[im][g * 4 + 2] = f32x2_t{b.x, b.y};
      xb[im][g * 4 + 3] = f32x2_t{b.z, b.w};
    }
  }

  // B-fragment base: wave hq, frag (c*2+jh, hq*2+ih), lane offset l*8
  const __hip_bfloat16* pw = frag + (size_t)hq * 1024 + lane * 8;

  f32x4_t acc[2][2];
#pragma unroll
  for (int im = 0; im < 2; ++im)
#pragma unroll
    for (int ih = 0; ih < 2; ++ih)
      acc[im][ih] = (f32x4_t)0.0f;

  bf16x8_t bn[2][2];
#pragma unroll
  for (int jh = 0; jh < 2; ++jh)
#pragma unroll
    for (int ih = 0; ih < 2; ++ih)
      bn[jh][ih] = *(const bf16x8_t*)(pw + jh * 4096 + ih * 512);

#pragma unroll
  for (int c = 0; c < 36; ++c) {
    bf16x8_t bc[2][2];
#pragma unroll
    for (int jh = 0; jh < 2; ++jh)
#pragma unroll
      for (int ih = 0; ih < 2; ++ih)
        bc[jh][ih] = bn[jh][ih];
    {  // prefetch chunk c+1
      const __hip_bfloat16* pn = pw + (size_t)(c + 1) * 8192;
#pragma unroll
      for (int jh = 0; jh < 2; ++jh)
#pragma unroll
        for (int ih = 0; ih < 2; ++ih)
          bn[jh][ih] = *(const bf16x8_t*)(pn + jh * 4096 + ih * 512);
    }
    const int I = CI[c], J = CJ[c];
#pragma unroll
    for (int jh = 0; jh < 2; ++jh) {
      bf16x8_t afrag[2];
#pragma unroll
      for (int im = 0; im < 2; ++im) {
        float s = sx[im][I * 8 + jh * 4 + q];   // LDS b32, 2-way max
        const f32x2_t s2 = f32x2_t{s, s};
        u32x4_t adv;
#pragma unroll
        for (int tt = 0; tt < 4; ++tt) {
          f32x2_t pr = s2 * xb[im][J * 4 + tt];          // v_pk_mul_f32
          u32x2_t u = __builtin_bit_cast(u32x2_t, pr);
          adv[tt] = __builtin_amdgcn_perm(u[1], u[0], 0x07060302);
        }
        afrag[im] = __builtin_bit_cast(bf16x8_t, adv);
      }
#pragma unroll
      for (int ih = 0; ih < 2; ++ih)
#pragma unroll
        for (int im = 0; im < 2; ++im)
          acc[im][ih] = __builtin_amdgcn_mfma_f32_16x16x32_bf16(
              afrag[im], bc[jh][ih], acc[im][ih], 0, 0, 0);
    }
  }

  // order-1 tail (chunk 36, bn holds its frags): A = x_j straight from LDS
#pragma unroll
  for (int jh = 0; jh < 2; ++jh) {
    bf16x8_t afrag[2];
#pragma unroll
    for (int im = 0; im < 2; ++im) {
      float4 a = *(const float4*)(sx[im] + jh * 32 + q * 8);
      float4 b = *(const float4*)(sx[im] + jh * 32 + q * 8 + 4);
      const float pr[4][2] = {{a.x, a.y}, {a.z, a.w}, {b.x, b.y}, {b.z, b.w}};
      u32x4_t adv;
#pragma unroll
      for (int tt = 0; tt < 4; ++tt)
        adv[tt] = __builtin_amdgcn_perm(__float_as_uint(pr[tt][1]),
                                        __float_as_uint(pr[tt][0]), 0x07060302);
      afrag[im] = __builtin_bit_cast(bf16x8_t, adv);
    }
#pragma unroll
    for (int ih = 0; ih < 2; ++ih)
#pragma unroll
      for (int im = 0; im < 2; ++im)
        acc[im][ih] = __builtin_amdgcn_mfma_f32_16x16x32_bf16(
            afrag[im], bn[jh][ih], acc[im][ih], 0, 0, 0);
  }

  // epilogue: a += bias; hw cos (input in revolutions); product over h
  float bs[2];
#pragma unroll
  for (int ih = 0; ih < 2; ++ih)
    bs[ih] = biasg[hq * 32 + ih * 16 + c15];

  const float INV2PI = 0.15915494309189535f;
  float prod[2][4];
#pragma unroll
  for (int im = 0; im < 2; ++im)
#pragma unroll
    for (int r = 0; r < 4; ++r) {
      float c0 = __builtin_amdgcn_cosf((acc[im][0][r] + bs[0]) * INV2PI);
      float c1 = __builtin_amdgcn_cosf((acc[im][1][r] + bs[1]) * INV2PI);
      prod[im][r] = c0 * c1;
    }

  // product across the 16 h-columns held by lanes (width-16 butterfly)
#pragma unroll
  for (int ofs = 1; ofs < 16; ofs <<= 1)
#pragma unroll
    for (int im = 0; im < 2; ++im)
#pragma unroll
      for (int r = 0; r < 4; ++r)
        prod[im][r] *= __shfl_xor(prod[im][r], ofs, 16);

  if (c15 == 0) {
#pragma unroll
    for (int im = 0; im < 2; ++im)
#pragma unroll
      for (int r = 0; r < 4; ++r)
        part[hq][wm * 32 + im * 16 + q * 4 + r] = prod[im][r];
  }
  __syncthreads();
  if (tid < 64) {
    float f = part[0][tid] * part[1][tid] * part[2][tid] * part[3][tid];
    outg[mblk + tid] = f;
  }
}

extern "C" void kernel_launch(void* const* d_in, const int* in_sizes, int n_in,
                              void* d_out, int out_size, void* d_ws, size_t ws_size,
                              hipStream_t stream) {
  const float* x   = (const float*)d_in[0];
  const float* w1f = (const float*)d_in[1];
  const float* w2f = (const float*)d_in[2];
  const float* hb  = (const float*)d_in[3];
  float* out = (float*)d_out;
  uint16_t* frag = (uint16_t*)d_ws;   // FRAG_ELEMS bf16 (592 KB)
  (void)in_sizes; (void)n_in; (void)out_size; (void)ws_size;

  cvt_kernel<<<148, 256, 0, stream>>>(w1f, w2f, frag);
  rbm_kernel<<<NB / 64, 512, 0, stream>>>(
      x, hb, (const __hip_bfloat16*)frag, out);
}